// Round 6
// baseline (303.783 us; speedup 1.0000x reference)
//
#include <hip/hip_runtime.h>

typedef __bf16 bf16;
typedef __bf16 bf16x8 __attribute__((ext_vector_type(8)));
typedef __bf16 bf16x4 __attribute__((ext_vector_type(4)));
typedef float  f32x4  __attribute__((ext_vector_type(4)));

#define T_TOTAL 9792
#define EMBED   1024
#define NHEAD   16
#define HDIM    64

// Fixed problem geometry (LENGTHS are compile-time constants of this problem).
__constant__ int c_seq_start[12]  = {0,1024,1792,2688,3200,4224,4864,5888,6656,7168,8064,9088};
__constant__ int c_tiles2_cum[13] = {0,8,14,21,25,33,38,46,52,56,63,71,77};   // 128-row q tiles
__constant__ int c_len64[12]      = {16,12,14,8,16,10,16,12,8,14,16,11};      // seq len / 64

typedef __attribute__((address_space(1))) unsigned int gu32;
typedef __attribute__((address_space(3))) unsigned int lu32;

__device__ __forceinline__ void load_lds16(const void* g, void* l) {
    __builtin_amdgcn_global_load_lds((gu32*)g, (lu32*)l, 16, 0, 0);
}

__device__ __forceinline__ f32x4 mfma16(bf16x8 a, bf16x8 b, f32x4 c) {
    return __builtin_amdgcn_mfma_f32_16x16x32_bf16(a, b, c, 0, 0, 0);
}

// ---------------------------------------------------------------------------
// Fused dtype canonicalization (one dispatch). disc: cos[0][0]==1.0 ->
// fp32 storage iff first u16 is 0x0000. Non-temporal loads (read-once src).
// ---------------------------------------------------------------------------
struct CvtArgs {
    const void* src[10];
    bf16*       dst[10];
    int         n[10];
    int         cum[10];
};

__global__ void to_bf16_fused(CvtArgs a, const unsigned short* __restrict__ disc)
{
    const bool f32 = (disc[0] == 0);
    const int blk = blockIdx.x;
    int seg = 0;
    #pragma unroll
    for (int i = 1; i < 10; ++i) if (blk >= a.cum[i]) seg = i;
    int i0 = (blk - a.cum[seg]) * 2048 + threadIdx.x * 8;
    if (i0 >= a.n[seg]) return;
    bf16x8 o;
    if (f32) {
        const f32x4* s = (const f32x4*)((const float*)a.src[seg] + i0);
        f32x4 x = __builtin_nontemporal_load(s);
        f32x4 y = __builtin_nontemporal_load(s + 1);
        o[0]=(bf16)x[0]; o[1]=(bf16)x[1]; o[2]=(bf16)x[2]; o[3]=(bf16)x[3];
        o[4]=(bf16)y[0]; o[5]=(bf16)y[1]; o[6]=(bf16)y[2]; o[7]=(bf16)y[3];
    } else {
        o = *(const bf16x8*)((const bf16*)a.src[seg] + i0);
    }
    *(bf16x8*)(a.dst[seg] + i0) = o;
}

// ---------------------------------------------------------------------------
// Shared GEMM core (m97 recipe, XOR-swizzled LDS, 0 bank conflicts verified).
// ---------------------------------------------------------------------------
__device__ __forceinline__
void gemm_core(const bf16* __restrict__ A, const bf16* __restrict__ W,
               int M, int m0, int n0, f32x4 (&acc)[4][4],
               bf16* lA, bf16* lB)
{
    const int tid  = threadIdx.x;
    const int wave = tid >> 6, lane = tid & 63;
    const int lrow = lane >> 3;
    const int gsw  = (lane & 7) ^ lrow;
    const int ln   = lane & 15, lq = lane >> 4;
    const int e7   = ln & 7;
    const int wm = (wave & 1) * 64,  wn = (wave >> 1) * 64;

    for (int k0 = 0; k0 < 1024; k0 += 64) {
        __syncthreads();
        for (int j = 0; j < 4; ++j) {
            int r = j * 32 + wave * 8;
            int gr = m0 + r + lrow; if (gr > M - 1) gr = M - 1;
            load_lds16(A + (size_t)gr * EMBED + k0 + gsw * 8, &lA[r * 64]);
            load_lds16(W + (size_t)(n0 + r + lrow) * EMBED + k0 + gsw * 8, &lB[r * 64]);
        }
        __syncthreads();
        #pragma unroll
        for (int kb = 0; kb < 2; ++kb) {
            bf16x8 af[4], bfr[4];
            #pragma unroll
            for (int i = 0; i < 4; ++i)
                af[i]  = *(const bf16x8*)&lA[(wm + i * 16 + ln) * 64 + (((kb * 4 + lq) ^ e7) * 8)];
            #pragma unroll
            for (int i = 0; i < 4; ++i)
                bfr[i] = *(const bf16x8*)&lB[(wn + i * 16 + ln) * 64 + (((kb * 4 + lq) ^ e7) * 8)];
            #pragma unroll
            for (int mi = 0; mi < 4; ++mi)
                #pragma unroll
                for (int ni = 0; ni < 4; ++ni)
                    acc[mi][ni] = mfma16(af[mi], bfr[ni], acc[mi][ni]);
        }
    }
}

// which-major 8x*8y supertiles: 2MB W-slab + 2MB A-slab ~ per-XCD L2.
// Per which: 616 blocks = 9 supercols of 64 + leftover 5x*8y.
__device__ __forceinline__ void map_sc(int r, int& x, int& y)
{
    if (r < 576) { int sc = r >> 6, q = r & 63; x = sc * 8 + (q & 7); y = q >> 3; }
    else         { int r2 = r - 576; x = 72 + (r2 % 5); y = r2 / 5; }
}

// ---------------------------------------------------------------------------
// QKV fused GEMM; epilogue fuses bias, RoPE (fp32 acc), V-transpose.
// ---------------------------------------------------------------------------
__global__ __launch_bounds__(256, 2)
void gemm_qkv(const bf16* __restrict__ A,
              const bf16* __restrict__ Wq, const bf16* __restrict__ Wk,
              const bf16* __restrict__ Wv, const bf16* __restrict__ qb,
              const bf16* __restrict__ vb,
              const bf16* __restrict__ cosb, const bf16* __restrict__ sinb,
              bf16* __restrict__ Cq, bf16* __restrict__ Ck,
              bf16* __restrict__ Vt, int M)
{
    __shared__ __align__(16) bf16 lA[128 * 64];
    __shared__ __align__(16) bf16 lB[128 * 64];

    const int which = blockIdx.x / 616;
    int x, yy;
    map_sc(blockIdx.x - which * 616, x, yy);
    const int m0 = x * 128, n0 = yy * 128;

    const bf16* W = (which == 0) ? Wq : (which == 1) ? Wk : Wv;
    f32x4 acc[4][4] = {};
    gemm_core(A, W, M, m0, n0, acc, lA, lB);

    const int tid  = threadIdx.x;
    const int wave = tid >> 6, lane = tid & 63;
    const int ln   = lane & 15, lq = lane >> 4;
    const int wm = (wave & 1) * 64,  wn = (wave >> 1) * 64;

    if (which < 2) {
        // Q or K: bias (Q only) + RoPE on fp32 acc. Pair (d, d+32) = (ni, ni+2).
        bf16* C = (which == 0) ? Cq : Ck;
        const bf16* bias = (which == 0) ? qb : nullptr;
        #pragma unroll
        for (int mi = 0; mi < 4; ++mi) {
            int trow = m0 + wm + mi * 16 + lq * 4;
            if (trow >= M) continue;
            #pragma unroll
            for (int ni = 0; ni < 2; ++ni) {
                int d    = ni * 16 + ln;           // in [0,32)
                int col0 = n0 + wn + d;
                int col1 = col0 + 32;
                float b0 = bias ? (float)bias[col0] : 0.0f;
                float b1 = bias ? (float)bias[col1] : 0.0f;
                #pragma unroll
                for (int r = 0; r < 4; ++r) {
                    int t = trow + r;
                    float c = (float)cosb[t * HDIM + d];
                    float s = (float)sinb[t * HDIM + d];
                    float x0 = acc[mi][ni][r] + b0;
                    float x1 = acc[mi][ni + 2][r] + b1;
                    C[(size_t)t * EMBED + col0] = (bf16)(x0 * c - x1 * s);
                    C[(size_t)t * EMBED + col1] = (bf16)(x1 * c + x0 * s);
                }
            }
        }
    } else {
        // V: bias + direct transposed store Vt[(h*64+d) * T + t]
        const int hd0 = n0 + wn;
        #pragma unroll
        for (int mi = 0; mi < 4; ++mi) {
            int trow = m0 + wm + mi * 16 + lq * 4;
            if (trow >= M) continue;
            #pragma unroll
            for (int ni = 0; ni < 4; ++ni) {
                int d = ni * 16 + ln;
                float bv = (float)vb[hd0 + d];
                bf16x4 o;
                #pragma unroll
                for (int r = 0; r < 4; ++r) o[r] = (bf16)(acc[mi][ni][r] + bv);
                *(bf16x4*)&Vt[(size_t)(hd0 + d) * T_TOTAL + trow] = o;
            }
        }
    }
}

// ---------------------------------------------------------------------------
// Out-proj GEMM: writes d_out directly (fp32 or bf16 per disc), non-temporal.
// ---------------------------------------------------------------------------
__global__ __launch_bounds__(256, 2)
void gemm_out(const bf16* __restrict__ A, const bf16* __restrict__ W,
              const bf16* __restrict__ bias, void* __restrict__ out, int M,
              const unsigned short* __restrict__ disc)
{
    __shared__ __align__(16) bf16 lA[128 * 64];
    __shared__ __align__(16) bf16 lB[128 * 64];

    int x, yy;
    map_sc(blockIdx.x, x, yy);
    const int m0 = x * 128, n0 = yy * 128;

    f32x4 acc[4][4] = {};
    gemm_core(A, W, M, m0, n0, acc, lA, lB);

    const bool f32 = (disc[0] == 0);
    const int tid  = threadIdx.x;
    const int wave = tid >> 6, lane = tid & 63;
    const int ln   = lane & 15, lq = lane >> 4;
    const int wm = (wave & 1) * 64,  wn = (wave >> 1) * 64;

    #pragma unroll
    for (int mi = 0; mi < 4; ++mi) {
        int trow = m0 + wm + mi * 16 + lq * 4;
        if (trow >= M) continue;
        #pragma unroll
        for (int ni = 0; ni < 4; ++ni) {
            int col = n0 + wn + ni * 16 + ln;
            float bv = (float)bias[col];
            #pragma unroll
            for (int r = 0; r < 4; ++r) {
                float v = acc[mi][ni][r] + bv;
                size_t idx = (size_t)(trow + r) * EMBED + col;
                if (f32) __builtin_nontemporal_store(v, (float*)out + idx);
                else     __builtin_nontemporal_store((bf16)v, (bf16*)out + idx);
            }
        }
    }
}

// ---------------------------------------------------------------------------
// Flash attention, S^T formulation, 128-q blocks.
// Each wave owns 32 q rows = 2 MFMA frags with INDEPENDENT online-softmax
// state; kf/vf LDS reads shared across both frags (halves LDS/MFMA ratio).
// Per-frag wave-uniform participation: frag (w,s) active at kv tile j iff
// 64j <= qmin+15 -> exact causal skipping at 16-row granularity.
// Seq 11 tail (rows >= T) : clamped loads, guarded stores.
// ---------------------------------------------------------------------------
__global__ __launch_bounds__(256, 3)
void attn_kernel(const bf16* __restrict__ Q, const bf16* __restrict__ K,
                 const bf16* __restrict__ Vt, bf16* __restrict__ O)
{
    __shared__ __align__(16) bf16 sK[2][64 * 64];
    __shared__ __align__(16) bf16 sV[2][64 * 64];       // Vt tile: [dh][kv]
    __shared__ __align__(16) bf16 sQP[4 * 32 * 72];     // Q tile (16KB) -> per-wave P (18KB)

    const int tid  = threadIdx.x;
    const int wave = tid >> 6, lane = tid & 63;
    const int lrow = lane >> 3;
    const int gsw  = (lane & 7) ^ lrow;
    const int ln   = lane & 15, lq = lane >> 4;
    const int e7   = ln & 7;
    const int h = blockIdx.y;

    int b = 0;
    #pragma unroll
    for (int i = 1; i < 13; ++i) if ((int)blockIdx.x >= c_tiles2_cum[i]) b = i;
    const int qt2 = blockIdx.x - c_tiles2_cum[b];
    const int s0  = c_seq_start[b];
    const int Q0r = qt2 * 128;                      // q offset relative to seq start
    const int nb  = c_len64[b];
    const int jmax = min(2 * qt2 + 1, nb - 1);

    // prologue: stage Q (128 rows) + K/V tile 0
    for (int p = 0; p < 4; ++p) {
        int r = p * 32 + wave * 8;
        int gr = s0 + Q0r + r + lrow; if (gr > T_TOTAL - 1) gr = T_TOTAL - 1;
        load_lds16(Q + (size_t)gr * EMBED + h * HDIM + gsw * 8, &sQP[r * 64]);
    }
    for (int p = 0; p < 2; ++p) {
        int r = p * 32 + wave * 8;
        load_lds16(K  + (size_t)(s0 + r + lrow) * EMBED + h * HDIM + gsw * 8, &sK[0][r * 64]);
        load_lds16(Vt + (size_t)(h * HDIM + r + lrow) * T_TOTAL + s0 + gsw * 8, &sV[0][r * 64]);
    }
    __syncthreads();

    bf16x8 qf[2][2];
    #pragma unroll
    for (int s = 0; s < 2; ++s)
        #pragma unroll
        for (int kk = 0; kk < 2; ++kk)
            qf[s][kk] = *(const bf16x8*)&sQP[(wave * 32 + s * 16 + ln) * 64 + ((kk * 4 + lq) ^ e7) * 8];
    __syncthreads();                                // sQP becomes sP from here

    f32x4 oacc[2][4] = {};
    float m_i[2] = {-1e30f, -1e30f}, l_i[2] = {0.0f, 0.0f};
    const float sc = 0.125f * 1.44269504088896f;    // 1/sqrt(64) * log2(e)
    const int qmin0 = Q0r + wave * 32;              // frag 0 q_min (seq-relative)
    bf16* sPw = &sQP[wave * 32 * 72];               // per-wave P rows [q32][72]

    for (int j = 0; j <= jmax; ++j) {
        const int cur = j & 1;
        if (j < jmax) {                             // prefetch next K/V tile
            const int kvb = s0 + (j + 1) * 64;
            const int nxt = cur ^ 1;
            for (int p = 0; p < 2; ++p) {
                int r = p * 32 + wave * 8;
                load_lds16(K  + (size_t)(kvb + r + lrow) * EMBED + h * HDIM + gsw * 8, &sK[nxt][r * 64]);
                load_lds16(Vt + (size_t)(h * HDIM + r + lrow) * T_TOTAL + kvb + gsw * 8, &sV[nxt][r * 64]);
            }
        }

        const int kv0 = j * 64;                     // seq-relative kv base
        const bool act0 = (kv0 <= qmin0 + 15);
        const bool act1 = (kv0 <= qmin0 + 31);      // frag1 q_min = qmin0+16

        bf16x8 kf[2][4];
        #pragma unroll
        for (int kk = 0; kk < 2; ++kk)
            #pragma unroll
            for (int ni = 0; ni < 4; ++ni)
                kf[kk][ni] = *(const bf16x8*)&sK[cur][(ni * 16 + ln) * 64 + ((kk * 4 + lq) ^ e7) * 8];

        #pragma unroll
        for (int s = 0; s < 2; ++s) {
            if (!(s ? act1 : act0)) continue;
            const int qmin = qmin0 + s * 16;

            f32x4 sa[4] = {};
            #pragma unroll
            for (int kk = 0; kk < 2; ++kk)
                #pragma unroll
                for (int ni = 0; ni < 4; ++ni)
                    sa[ni] = mfma16(kf[kk][ni], qf[s][kk], sa[ni]);   // S^T[kv][q]

            float pb[4][4];
            if (kv0 + 63 > qmin) {                  // diagonal tile for this frag
                int qloc = qmin + ln;
                #pragma unroll
                for (int ni = 0; ni < 4; ++ni)
                    #pragma unroll
                    for (int r = 0; r < 4; ++r) {
                        int kv = kv0 + ni * 16 + lq * 4 + r;
                        pb[ni][r] = (kv <= qloc) ? sa[ni][r] * sc : -1e30f;
                    }
            } else {
                #pragma unroll
                for (int ni = 0; ni < 4; ++ni)
                    #pragma unroll
                    for (int r = 0; r < 4; ++r)
                        pb[ni][r] = sa[ni][r] * sc;
            }

            float mx = pb[0][0];
            #pragma unroll
            for (int ni = 0; ni < 4; ++ni)
                #pragma unroll
                for (int r = 0; r < 4; ++r) mx = fmaxf(mx, pb[ni][r]);
            mx = fmaxf(mx, __shfl_xor(mx, 16));
            mx = fmaxf(mx, __shfl_xor(mx, 32));
            float mnew  = fmaxf(m_i[s], mx);
            float alpha = exp2f(m_i[s] - mnew);
            m_i[s] = mnew;

            float rs = 0.0f;
            #pragma unroll
            for (int ni = 0; ni < 4; ++ni)
                #pragma unroll
                for (int r = 0; r < 4; ++r) {
                    float pe = exp2f(pb[ni][r] - mnew);
                    pb[ni][r] = pe;
                    rs += pe;
                }
            rs += __shfl_xor(rs, 16);
            rs += __shfl_xor(rs, 32);
            l_i[s] = l_i[s] * alpha + rs;
            #pragma unroll
            for (int d = 0; d < 4; ++d)
                #pragma unroll
                for (int r = 0; r < 4; ++r) oacc[s][d][r] *= alpha;

            #pragma unroll
            for (int ni = 0; ni < 4; ++ni) {
                bf16x4 w4;
                #pragma unroll
                for (int r = 0; r < 4; ++r) w4[r] = (bf16)pb[ni][r];
                *(bf16x4*)&sPw[(s * 16 + ln) * 72 + ni * 16 + lq * 4] = w4;
            }
        }
        asm volatile("s_waitcnt lgkmcnt(0)" ::: "memory");  // same-wave sP visibility

        #pragma unroll
        for (int kk = 0; kk < 2; ++kk) {
            bf16x8 pf0, pf1;
            if (act0) pf0 = *(const bf16x8*)&sPw[(0 * 16 + ln) * 72 + kk * 32 + lq * 8];
            if (act1) pf1 = *(const bf16x8*)&sPw[(1 * 16 + ln) * 72 + kk * 32 + lq * 8];
            #pragma unroll
            for (int d = 0; d < 4; ++d) {
                bf16x8 vf = *(const bf16x8*)&sV[cur][(d * 16 + ln) * 64 + ((kk * 4 + lq) ^ e7) * 8];
                if (act0) oacc[0][d] = mfma16(vf, pf0, oacc[0][d]);   // O^T[dh][q]
                if (act1) oacc[1][d] = mfma16(vf, pf1, oacc[1][d]);
            }
        }
        __syncthreads();   // staging (vmcnt drained) + all cur-reads done
    }

    // O^T C-layout per frag: col = ln = q, row = lq*4+r = dh (within d-tile)
    #pragma unroll
    for (int s = 0; s < 2; ++s) {
        int qg = s0 + Q0r + wave * 32 + s * 16 + ln;
        if (qg >= T_TOTAL) continue;
        const float inv = 1.0f / l_i[s];
        const size_t base = (size_t)qg * EMBED + h * HDIM;
        #pragma unroll
        for (int d = 0; d < 4; ++d) {
            bf16x4 o4;
            #pragma unroll
            for (int r = 0; r < 4; ++r) o4[r] = (bf16)(oacc[s][d][r] * inv);
            *(bf16x4*)&O[base + d * 16 + lq * 4] = o4;
        }
    }
}

// ---------------------------------------------------------------------------
extern "C" void kernel_launch(void* const* d_in, const int* in_sizes, int n_in,
                              void* d_out, int out_size, void* d_ws, size_t ws_size,
                              hipStream_t stream)
{
    const unsigned short* disc = (const unsigned short*)d_in[1];  // cos[0][0]

    const size_t SZ  = (size_t)T_TOTAL * EMBED;   // 10,027,008
    const size_t CS  = (size_t)T_TOTAL * HDIM;    // 626,688
    const size_t WSZ = (size_t)EMBED * EMBED;     // 1,048,576

    bf16* p = (bf16*)d_ws;
    bf16* ch   = p; p += SZ;
    bf16* ccos = p; p += CS;
    bf16* csin = p; p += CS;
    bf16* cqw  = p; p += WSZ;
    bf16* ckw  = p; p += WSZ;
    bf16* cvw  = p; p += WSZ;
    bf16* cow  = p; p += WSZ;
    bf16* cqb  = p; p += EMBED;
    bf16* cvb  = p; p += EMBED;
    bf16* cob  = p; p += EMBED;
    bf16* wq   = p; p += SZ;      // Q (post-RoPE), then attention output (in place)
    bf16* wk   = p; p += SZ;
    bf16* wvt  = p; p += SZ;      // V^T per head

    CvtArgs ca;
    const void* srcs[10] = {d_in[0], d_in[1], d_in[2], d_in[3], d_in[5],
                            d_in[6], d_in[8], d_in[4], d_in[7], d_in[9]};
    bf16* dsts[10] = {ch, ccos, csin, cqw, ckw, cvw, cow, cqb, cvb, cob};
    int   ns[10]   = {(int)SZ, (int)CS, (int)CS, (int)WSZ, (int)WSZ,
                      (int)WSZ, (int)WSZ, EMBED, EMBED, EMBED};
    int cum = 0;
    for (int i = 0; i < 10; ++i) {
        ca.src[i] = srcs[i]; ca.dst[i] = dsts[i]; ca.n[i] = ns[i];
        ca.cum[i] = cum;
        cum += (ns[i] + 2047) / 2048;
    }
    to_bf16_fused<<<cum, 256, 0, stream>>>(ca, disc);

    gemm_qkv<<<3 * 616, 256, 0, stream>>>(ch, cqw, ckw, cvw, cqb, cvb,
                                          ccos, csin, wq, wk, wvt, T_TOTAL);
    attn_kernel<<<dim3(77, 16), 256, 0, stream>>>(wq, wk, wvt, wq);
    gemm_out<<<616, 256, 0, stream>>>(wq, cow, cob, d_out, T_TOTAL, disc);
}

// Round 7
// 294.633 us; speedup vs baseline: 1.0311x; 1.0311x over previous
//
#include <hip/hip_runtime.h>

typedef __bf16 bf16;
typedef __bf16 bf16x8 __attribute__((ext_vector_type(8)));
typedef __bf16 bf16x4 __attribute__((ext_vector_type(4)));
typedef float  f32x4  __attribute__((ext_vector_type(4)));

#define T_TOTAL 9792
#define EMBED   1024
#define NHEAD   16
#define HDIM    64

// Fixed problem geometry.
__constant__ int c_seq_start[12] = {0,1024,1792,2688,3200,4224,4864,5888,6656,7168,8064,9088};

// Longest-first schedule: 153 (qt,b) pairs encoded (qt<<4)|b, descending qt.
// Long causal diagonals dispatch first -> minimal tail imbalance.
__constant__ unsigned char c_order[153] = {
  240,244,246,250,
  224,228,230,234,
  208,210,212,214,217,218,
  192,194,196,198,201,202,
  176,177,178,180,182,183,185,186,
  160,161,162,164,166,167,169,170,171,
  144,145,146,148,149,150,151,153,154,155,
  128,129,130,132,133,134,135,137,138,139,
  112,113,114,115,116,117,118,119,120,121,122,123,
  96,97,98,99,100,101,102,103,104,105,106,107,
  80,81,82,83,84,85,86,87,88,89,90,91,
  64,65,66,67,68,69,70,71,72,73,74,75,
  48,49,50,51,52,53,54,55,56,57,58,59,
  32,33,34,35,36,37,38,39,40,41,42,43,
  16,17,18,19,20,21,22,23,24,25,26,27,
  0,1,2,3,4,5,6,7,8,9,10,11
};

typedef __attribute__((address_space(1))) unsigned int gu32;
typedef __attribute__((address_space(3))) unsigned int lu32;

__device__ __forceinline__ void load_lds16(const void* g, void* l) {
    __builtin_amdgcn_global_load_lds((gu32*)g, (lu32*)l, 16, 0, 0);
}

__device__ __forceinline__ f32x4 mfma16(bf16x8 a, bf16x8 b, f32x4 c) {
    return __builtin_amdgcn_mfma_f32_16x16x32_bf16(a, b, c, 0, 0, 0);
}

// ---------------------------------------------------------------------------
// Fused dtype canonicalization (one dispatch). disc: cos[0][0]==1.0 ->
// fp32 storage iff first u16 is 0x0000. Non-temporal loads (read-once src).
// ---------------------------------------------------------------------------
struct CvtArgs {
    const void* src[10];
    bf16*       dst[10];
    int         n[10];
    int         cum[10];
};

__global__ void to_bf16_fused(CvtArgs a, const unsigned short* __restrict__ disc)
{
    const bool f32 = (disc[0] == 0);
    const int blk = blockIdx.x;
    int seg = 0;
    #pragma unroll
    for (int i = 1; i < 10; ++i) if (blk >= a.cum[i]) seg = i;
    int i0 = (blk - a.cum[seg]) * 2048 + threadIdx.x * 8;
    if (i0 >= a.n[seg]) return;
    bf16x8 o;
    if (f32) {
        const f32x4* s = (const f32x4*)((const float*)a.src[seg] + i0);
        f32x4 x = __builtin_nontemporal_load(s);
        f32x4 y = __builtin_nontemporal_load(s + 1);
        o[0]=(bf16)x[0]; o[1]=(bf16)x[1]; o[2]=(bf16)x[2]; o[3]=(bf16)x[3];
        o[4]=(bf16)y[0]; o[5]=(bf16)y[1]; o[6]=(bf16)y[2]; o[7]=(bf16)y[3];
    } else {
        o = *(const bf16x8*)((const bf16*)a.src[seg] + i0);
    }
    *(bf16x8*)(a.dst[seg] + i0) = o;
}

// ---------------------------------------------------------------------------
// Shared GEMM core (m97 recipe, XOR-swizzled LDS, 0 bank conflicts verified).
// ---------------------------------------------------------------------------
__device__ __forceinline__
void gemm_core(const bf16* __restrict__ A, const bf16* __restrict__ W,
               int M, int m0, int n0, f32x4 (&acc)[4][4],
               bf16* lA, bf16* lB)
{
    const int tid  = threadIdx.x;
    const int wave = tid >> 6, lane = tid & 63;
    const int lrow = lane >> 3;
    const int gsw  = (lane & 7) ^ lrow;
    const int ln   = lane & 15, lq = lane >> 4;
    const int e7   = ln & 7;
    const int wm = (wave & 1) * 64,  wn = (wave >> 1) * 64;

    for (int k0 = 0; k0 < 1024; k0 += 64) {
        __syncthreads();
        for (int j = 0; j < 4; ++j) {
            int r = j * 32 + wave * 8;
            int gr = m0 + r + lrow; if (gr > M - 1) gr = M - 1;
            load_lds16(A + (size_t)gr * EMBED + k0 + gsw * 8, &lA[r * 64]);
            load_lds16(W + (size_t)(n0 + r + lrow) * EMBED + k0 + gsw * 8, &lB[r * 64]);
        }
        __syncthreads();
        #pragma unroll
        for (int kb = 0; kb < 2; ++kb) {
            bf16x8 af[4], bfr[4];
            #pragma unroll
            for (int i = 0; i < 4; ++i)
                af[i]  = *(const bf16x8*)&lA[(wm + i * 16 + ln) * 64 + (((kb * 4 + lq) ^ e7) * 8)];
            #pragma unroll
            for (int i = 0; i < 4; ++i)
                bfr[i] = *(const bf16x8*)&lB[(wn + i * 16 + ln) * 64 + (((kb * 4 + lq) ^ e7) * 8)];
            #pragma unroll
            for (int mi = 0; mi < 4; ++mi)
                #pragma unroll
                for (int ni = 0; ni < 4; ++ni)
                    acc[mi][ni] = mfma16(af[mi], bfr[ni], acc[mi][ni]);
        }
    }
}

// which-major 8x*8y supertiles: 2MB W-slab + 2MB A-slab ~ per-XCD L2.
__device__ __forceinline__ void map_sc(int r, int& x, int& y)
{
    if (r < 576) { int sc = r >> 6, q = r & 63; x = sc * 8 + (q & 7); y = q >> 3; }
    else         { int r2 = r - 576; x = 72 + (r2 % 5); y = r2 / 5; }
}

// ---------------------------------------------------------------------------
// QKV fused GEMM; epilogue fuses bias, RoPE (fp32 acc), V-transpose.
// ---------------------------------------------------------------------------
__global__ __launch_bounds__(256, 2)
void gemm_qkv(const bf16* __restrict__ A,
              const bf16* __restrict__ Wq, const bf16* __restrict__ Wk,
              const bf16* __restrict__ Wv, const bf16* __restrict__ qb,
              const bf16* __restrict__ vb,
              const bf16* __restrict__ cosb, const bf16* __restrict__ sinb,
              bf16* __restrict__ Cq, bf16* __restrict__ Ck,
              bf16* __restrict__ Vt, int M)
{
    __shared__ __align__(16) bf16 lA[128 * 64];
    __shared__ __align__(16) bf16 lB[128 * 64];

    const int which = blockIdx.x / 616;
    int x, yy;
    map_sc(blockIdx.x - which * 616, x, yy);
    const int m0 = x * 128, n0 = yy * 128;

    const bf16* W = (which == 0) ? Wq : (which == 1) ? Wk : Wv;
    f32x4 acc[4][4] = {};
    gemm_core(A, W, M, m0, n0, acc, lA, lB);

    const int tid  = threadIdx.x;
    const int wave = tid >> 6, lane = tid & 63;
    const int ln   = lane & 15, lq = lane >> 4;
    const int wm = (wave & 1) * 64,  wn = (wave >> 1) * 64;

    if (which < 2) {
        bf16* C = (which == 0) ? Cq : Ck;
        const bf16* bias = (which == 0) ? qb : nullptr;
        #pragma unroll
        for (int mi = 0; mi < 4; ++mi) {
            int trow = m0 + wm + mi * 16 + lq * 4;
            if (trow >= M) continue;
            #pragma unroll
            for (int ni = 0; ni < 2; ++ni) {
                int d    = ni * 16 + ln;
                int col0 = n0 + wn + d;
                int col1 = col0 + 32;
                float b0 = bias ? (float)bias[col0] : 0.0f;
                float b1 = bias ? (float)bias[col1] : 0.0f;
                #pragma unroll
                for (int r = 0; r < 4; ++r) {
                    int t = trow + r;
                    float c = (float)cosb[t * HDIM + d];
                    float s = (float)sinb[t * HDIM + d];
                    float x0 = acc[mi][ni][r] + b0;
                    float x1 = acc[mi][ni + 2][r] + b1;
                    C[(size_t)t * EMBED + col0] = (bf16)(x0 * c - x1 * s);
                    C[(size_t)t * EMBED + col1] = (bf16)(x1 * c + x0 * s);
                }
            }
        }
    } else {
        const int hd0 = n0 + wn;
        #pragma unroll
        for (int mi = 0; mi < 4; ++mi) {
            int trow = m0 + wm + mi * 16 + lq * 4;
            if (trow >= M) continue;
            #pragma unroll
            for (int ni = 0; ni < 4; ++ni) {
                int d = ni * 16 + ln;
                float bv = (float)vb[hd0 + d];
                bf16x4 o;
                #pragma unroll
                for (int r = 0; r < 4; ++r) o[r] = (bf16)(acc[mi][ni][r] + bv);
                *(bf16x4*)&Vt[(size_t)(hd0 + d) * T_TOTAL + trow] = o;
            }
        }
    }
}

// ---------------------------------------------------------------------------
// Out-proj GEMM: writes d_out directly (fp32 or bf16 per disc), non-temporal.
// ---------------------------------------------------------------------------
__global__ __launch_bounds__(256, 2)
void gemm_out(const bf16* __restrict__ A, const bf16* __restrict__ W,
              const bf16* __restrict__ bias, void* __restrict__ out, int M,
              const unsigned short* __restrict__ disc)
{
    __shared__ __align__(16) bf16 lA[128 * 64];
    __shared__ __align__(16) bf16 lB[128 * 64];

    int x, yy;
    map_sc(blockIdx.x, x, yy);
    const int m0 = x * 128, n0 = yy * 128;

    f32x4 acc[4][4] = {};
    gemm_core(A, W, M, m0, n0, acc, lA, lB);

    const bool f32 = (disc[0] == 0);
    const int tid  = threadIdx.x;
    const int wave = tid >> 6, lane = tid & 63;
    const int ln   = lane & 15, lq = lane >> 4;
    const int wm = (wave & 1) * 64,  wn = (wave >> 1) * 64;

    #pragma unroll
    for (int mi = 0; mi < 4; ++mi) {
        int trow = m0 + wm + mi * 16 + lq * 4;
        if (trow >= M) continue;
        #pragma unroll
        for (int ni = 0; ni < 4; ++ni) {
            int col = n0 + wn + ni * 16 + ln;
            float bv = (float)bias[col];
            #pragma unroll
            for (int r = 0; r < 4; ++r) {
                float v = acc[mi][ni][r] + bv;
                size_t idx = (size_t)(trow + r) * EMBED + col;
                if (f32) __builtin_nontemporal_store(v, (float*)out + idx);
                else     __builtin_nontemporal_store((bf16)v, (bf16*)out + idx);
            }
        }
    }
}

// ---------------------------------------------------------------------------
// Flash attention, S^T formulation, 64-q blocks (R4 structure — verified
// faster than 128-q: occupancy/block-count wins over per-iter LDS savings).
// Longest-first (qt descending) static schedule via c_order.
// ---------------------------------------------------------------------------
__global__ __launch_bounds__(256, 3)
void attn_kernel(const bf16* __restrict__ Q, const bf16* __restrict__ K,
                 const bf16* __restrict__ Vt, bf16* __restrict__ O)
{
    __shared__ __align__(16) bf16 sK[2][64 * 64];
    __shared__ __align__(16) bf16 sV[2][64 * 64];       // Vt tile: [dh][kv]
    __shared__ __align__(16) bf16 sQP[4 * 16 * 72];     // Q tile (8KB) -> per-wave P

    const int tid  = threadIdx.x;
    const int wave = tid >> 6, lane = tid & 63;
    const int lrow = lane >> 3;
    const int gsw  = (lane & 7) ^ lrow;
    const int ln   = lane & 15, lq = lane >> 4;
    const int e7   = ln & 7;
    const int h = blockIdx.y;

    const int code = c_order[blockIdx.x];
    const int b  = code & 15;
    const int qt = code >> 4;
    const int t0 = c_seq_start[b] + qt * 64;
    const int kvb0 = c_seq_start[b];

    for (int p = 0; p < 2; ++p) {
        int r = p * 32 + wave * 8;
        load_lds16(Q  + (size_t)(t0 + r + lrow) * EMBED + h * HDIM + gsw * 8, &sQP[r * 64]);
        load_lds16(K  + (size_t)(kvb0 + r + lrow) * EMBED + h * HDIM + gsw * 8, &sK[0][r * 64]);
        load_lds16(Vt + (size_t)(h * HDIM + r + lrow) * T_TOTAL + kvb0 + gsw * 8, &sV[0][r * 64]);
    }

    bf16x8 qf[2];
    f32x4 oacc[4] = {};
    float m_i = -1e30f, l_i = 0.0f;
    const float sc = 0.125f * 1.44269504088896f;        // 1/sqrt(64) * log2(e)
    const int q_loc = wave * 16 + ln;
    bf16* sP = &sQP[wave * 16 * 72];

    for (int j = 0; j <= qt; ++j) {
        __syncthreads();
        const int cur = j & 1;
        if (j == 0) {
            qf[0] = *(const bf16x8*)&sQP[q_loc * 64 + ((0 + lq) ^ e7) * 8];
            qf[1] = *(const bf16x8*)&sQP[q_loc * 64 + ((4 + lq) ^ e7) * 8];
            __syncthreads();                            // sQP becomes sP
        }
        if (j < qt) {
            const int kvb = kvb0 + (j + 1) * 64;
            const int nxt = cur ^ 1;
            for (int p = 0; p < 2; ++p) {
                int r = p * 32 + wave * 8;
                load_lds16(K  + (size_t)(kvb + r + lrow) * EMBED + h * HDIM + gsw * 8, &sK[nxt][r * 64]);
                load_lds16(Vt + (size_t)(h * HDIM + r + lrow) * T_TOTAL + kvb + gsw * 8, &sV[nxt][r * 64]);
            }
        }

        f32x4 s[4] = {};
        #pragma unroll
        for (int kk = 0; kk < 2; ++kk)
            #pragma unroll
            for (int ni = 0; ni < 4; ++ni) {
                bf16x8 kf = *(const bf16x8*)&sK[cur][(ni * 16 + ln) * 64 + ((kk * 4 + lq) ^ e7) * 8];
                s[ni] = mfma16(kf, qf[kk], s[ni]);      // S^T[kv][q]
            }

        float pb[4][4];
        if (j == qt) {
            #pragma unroll
            for (int ni = 0; ni < 4; ++ni)
                #pragma unroll
                for (int r = 0; r < 4; ++r) {
                    int kv = ni * 16 + lq * 4 + r;
                    pb[ni][r] = (kv <= q_loc) ? s[ni][r] * sc : -1e30f;
                }
        } else {
            #pragma unroll
            for (int ni = 0; ni < 4; ++ni)
                #pragma unroll
                for (int r = 0; r < 4; ++r)
                    pb[ni][r] = s[ni][r] * sc;
        }

        float mx = pb[0][0];
        #pragma unroll
        for (int ni = 0; ni < 4; ++ni)
            #pragma unroll
            for (int r = 0; r < 4; ++r) mx = fmaxf(mx, pb[ni][r]);
        mx = fmaxf(mx, __shfl_xor(mx, 16));
        mx = fmaxf(mx, __shfl_xor(mx, 32));
        float mnew  = fmaxf(m_i, mx);
        float alpha = exp2f(m_i - mnew);
        m_i = mnew;

        float rs = 0.0f;
        #pragma unroll
        for (int ni = 0; ni < 4; ++ni)
            #pragma unroll
            for (int r = 0; r < 4; ++r) {
                float pe = exp2f(pb[ni][r] - mnew);
                pb[ni][r] = pe;
                rs += pe;
            }
        rs += __shfl_xor(rs, 16);
        rs += __shfl_xor(rs, 32);
        l_i = l_i * alpha + rs;
        #pragma unroll
        for (int d = 0; d < 4; ++d)
            #pragma unroll
            for (int r = 0; r < 4; ++r) oacc[d][r] *= alpha;

        #pragma unroll
        for (int ni = 0; ni < 4; ++ni) {
            bf16x4 w4;
            #pragma unroll
            for (int r = 0; r < 4; ++r) w4[r] = (bf16)pb[ni][r];
            *(bf16x4*)&sP[ln * 72 + ni * 16 + lq * 4] = w4;
        }
        asm volatile("s_waitcnt lgkmcnt(0)" ::: "memory");

        #pragma unroll
        for (int kk = 0; kk < 2; ++kk) {
            bf16x8 pf = *(const bf16x8*)&sP[ln * 72 + kk * 32 + lq * 8];
            #pragma unroll
            for (int d = 0; d < 4; ++d) {
                bf16x8 vf = *(const bf16x8*)&sV[cur][(d * 16 + ln) * 64 + ((kk * 4 + lq) ^ e7) * 8];
                oacc[d] = mfma16(vf, pf, oacc[d]);      // O^T[dh][q]
            }
        }
    }

    const float inv = 1.0f / l_i;
    const size_t row = (size_t)(t0 + q_loc) * EMBED + h * HDIM;
    #pragma unroll
    for (int d = 0; d < 4; ++d) {
        bf16x4 o4;
        #pragma unroll
        for (int r = 0; r < 4; ++r) o4[r] = (bf16)(oacc[d][r] * inv);
        *(bf16x4*)&O[row + d * 16 + lq * 4] = o4;
    }
}

// ---------------------------------------------------------------------------
extern "C" void kernel_launch(void* const* d_in, const int* in_sizes, int n_in,
                              void* d_out, int out_size, void* d_ws, size_t ws_size,
                              hipStream_t stream)
{
    const unsigned short* disc = (const unsigned short*)d_in[1];  // cos[0][0]

    const size_t SZ  = (size_t)T_TOTAL * EMBED;   // 10,027,008
    const size_t CS  = (size_t)T_TOTAL * HDIM;    // 626,688
    const size_t WSZ = (size_t)EMBED * EMBED;     // 1,048,576

    bf16* p = (bf16*)d_ws;
    bf16* ch   = p; p += SZ;
    bf16* ccos = p; p += CS;
    bf16* csin = p; p += CS;
    bf16* cqw  = p; p += WSZ;
    bf16* ckw  = p; p += WSZ;
    bf16* cvw  = p; p += WSZ;
    bf16* cow  = p; p += WSZ;
    bf16* cqb  = p; p += EMBED;
    bf16* cvb  = p; p += EMBED;
    bf16* cob  = p; p += EMBED;
    bf16* wq   = p; p += SZ;      // Q (post-RoPE), then attention output (in place)
    bf16* wk   = p; p += SZ;
    bf16* wvt  = p; p += SZ;      // V^T per head

    CvtArgs ca;
    const void* srcs[10] = {d_in[0], d_in[1], d_in[2], d_in[3], d_in[5],
                            d_in[6], d_in[8], d_in[4], d_in[7], d_in[9]};
    bf16* dsts[10] = {ch, ccos, csin, cqw, ckw, cvw, cow, cqb, cvb, cob};
    int   ns[10]   = {(int)SZ, (int)CS, (int)CS, (int)WSZ, (int)WSZ,
                      (int)WSZ, (int)WSZ, EMBED, EMBED, EMBED};
    int cum = 0;
    for (int i = 0; i < 10; ++i) {
        ca.src[i] = srcs[i]; ca.dst[i] = dsts[i]; ca.n[i] = ns[i];
        ca.cum[i] = cum;
        cum += (ns[i] + 2047) / 2048;
    }
    to_bf16_fused<<<cum, 256, 0, stream>>>(ca, disc);

    gemm_qkv<<<3 * 616, 256, 0, stream>>>(ch, cqw, ckw, cvw, cqb, cvb,
                                          ccos, csin, wq, wk, wvt, T_TOTAL);
    attn_kernel<<<dim3(153, 16), 256, 0, stream>>>(wq, wk, wvt, wq);
    gemm_out<<<616, 256, 0, stream>>>(wq, cow, cob, d_out, T_TOTAL, disc);
}